// Round 16
// baseline (123.482 us; speedup 1.0000x reference)
//
#include <hip/hip_runtime.h>

typedef __bf16 bf16;
typedef bf16 bf16x8 __attribute__((ext_vector_type(8)));
typedef bf16 bf16x4 __attribute__((ext_vector_type(4)));
typedef bf16 bf16x2 __attribute__((ext_vector_type(2)));
typedef float f32x4 __attribute__((ext_vector_type(4)));
typedef unsigned long long u64;
typedef unsigned int u32;

#define B_SZ 8
#define N_SEQ 1024
#define DMODEL 512
#define N_HEADS 8
#define D_HEAD 64
#define M_ROWS 8192   // B_SZ * N_SEQ

// Q pre-scale: 1/sqrt(64) * log2(e), so softmax uses exp2 directly
#define QSCALE 0.18033688011112042f

// ---- workspace layout (bytes) ----
static constexpr size_t OFF_XB   = 0;                                   // bf16 [8192][512]; reused as attn_out later
static constexpr size_t OFF_WQKV = (size_t)M_ROWS * DMODEL * 2;         // bf16 [1536][512]
static constexpr size_t OFF_WO   = OFF_WQKV + (size_t)1536 * 512 * 2;   // bf16 [512][512]
static constexpr size_t OFF_BQKV = OFF_WO + (size_t)512 * 512 * 2;      // f32  [1536]
static constexpr size_t OFF_Q    = OFF_BQKV + 1536 * 4;                 // bf16 [64][1024][64]; later reused as h bf16
static constexpr size_t OFF_K    = OFF_Q + (size_t)64 * 1024 * 64 * 2;
static constexpr size_t OFF_V    = OFF_K + (size_t)64 * 1024 * 64 * 2;  // V^T: bf16 [64 bh][64 d][1024 n]
static constexpr size_t OFF_MASK = OFF_V + (size_t)64 * 1024 * 64 * 2;  // u64 [8][1024][16]

// k_prep block partition (256 threads each): x-cvt + wqkv + bias only
#define PREP_X_BLK 4096    // 8192*512 elems / 4-per-thread / 256
#define PREP_W_BLK 3078    // (1536*512 + 1536 + 255) / 256

// hetero GEMM-1 grid partition: GEMM blocks, then mask-build, then wo-pack
#define G1_GEMM 768        // (8192/128)*(1536/128)
#define G1_MASK 32768      // 8*1024*1024 / 256
#define G1_WO   1024       // 512*512 / 256

__device__ __forceinline__ f32x4 mfma16(bf16x8 a, bf16x8 b, f32x4 c) {
  return __builtin_amdgcn_mfma_f32_16x16x32_bf16(a, b, c, 0, 0, 0);
}

// XOR swizzle for [R][64] bf16 LDS tiles (row = 128B) -- guide G4 / T2.
__device__ __forceinline__ int sidx(int row, int col) {
  return (row << 6) + (col ^ ((row & 7) << 3));
}

// async global->LDS, 16B per lane; LDS dest = wave-uniform base + lane*16.
__device__ __forceinline__ void gload16(const void* g, void* l) {
  __builtin_amdgcn_global_load_lds(
      (const __attribute__((address_space(1))) void*)g,
      (__attribute__((address_space(3))) void*)l, 16, 0, 0);
}

// ---- prep: cvt x, pack wqkv + biases (mask/wo moved into hetero GEMM-1) ----
__global__ void k_prep(const float* __restrict__ x,
                       const float* __restrict__ Wq, const float* __restrict__ Wk,
                       const float* __restrict__ Wv,
                       const float* __restrict__ bq, const float* __restrict__ bk,
                       const float* __restrict__ bv,
                       bf16* __restrict__ xb, bf16* __restrict__ wqkv,
                       float* __restrict__ bqkv) {
  int b = blockIdx.x;
  if (b < PREP_X_BLK) {                 // x fp32 -> bf16, 4/thread
    int i = b * 256 + threadIdx.x;
    float4 v = reinterpret_cast<const float4*>(x)[i];
    bf16x4 o = { (bf16)v.x, (bf16)v.y, (bf16)v.z, (bf16)v.w };
    *reinterpret_cast<bf16x4*>(xb + (size_t)i * 4) = o;
  } else {                              // wqkv + bqkv
    int tid = (b - PREP_X_BLK) * 256 + threadIdx.x;
    if (tid < 1536 * 512) {
      int row = tid >> 9;
      const float* Wsrc = row < 512 ? Wq : row < 1024 ? Wk : Wv;
      wqkv[tid] = (bf16)Wsrc[((row & 511) << 9) | (tid & 511)];
    } else if (tid < 1536 * 512 + 1536) {
      int t = tid - 1536 * 512;
      bqkv[t] = t < 512 ? bq[t] : t < 1024 ? bk[t - 512] : bv[t - 1024];
    }
  }
}

// ---- hetero kernel: QKV GEMM (mode-0) + adjacency mask build + wo pack ----
// GEMM blocks (0..767) dispatch first, fill ~3 blocks/CU (compute-bound);
// mask blocks backfill remaining wave/LDS slots and stream the 32MB adj read
// from HBM UNDER the GEMM's MFMA (GEMM leaves HBM mostly idle). No cross-
// block dependencies: maskb/wo are consumed only by LATER kernels.
__global__ __launch_bounds__(256) void k_gemm1f(const bf16* __restrict__ A,
    const bf16* __restrict__ W, const float* __restrict__ bias,
    bf16* __restrict__ oq, bf16* __restrict__ okk, bf16* __restrict__ ov,
    const float* __restrict__ adj, const float* __restrict__ Wo,
    bf16* __restrict__ wo, u64* __restrict__ maskb) {
  __shared__ bf16 Al[128 * 64];
  __shared__ bf16 Bl[128 * 64];
  int bid = blockIdx.x;

  if (bid >= G1_GEMM + G1_MASK) {       // ---- wo pack ----
    int t = (bid - G1_GEMM - G1_MASK) * 256 + threadIdx.x;
    wo[t] = (bf16)Wo[t];
    return;
  }
  if (bid >= G1_GEMM) {                 // ---- mask bits (self-loops OR'd) ----
    int idx = (bid - G1_GEMM) * 256 + threadIdx.x;
    int q = (idx >> 10) & 1023, k = idx & 1023;
    bool pred = (adj[idx] > 0.f) || (q == k);
    u64 bal = __ballot(pred);
    if ((threadIdx.x & 63) == 0) maskb[idx >> 6] = bal;
    return;
  }

  // ---- QKV GEMM body (m97 structure, T1 swizzle over the 768-subgrid) ----
  const int nbx = 12;                   // 1536/128
  int wid = (bid & 7) * (G1_GEMM / 8) + (bid >> 3);
  int bx = wid % nbx, by = wid / nbx;
  int m0 = by << 7, n0 = bx << 7;
  int tid = threadIdx.x, lane = tid & 63, w = tid >> 6;
  int wr = (w >> 1) << 6, wc = (w & 1) << 6;
  int lrow = lane & 15, lg = lane >> 4, lko = lg * 8;
  int rl = lane >> 3;                   // row-in-group 0..7
  int csw = ((lane & 7) ^ rl) << 3;     // pre-swizzled col (elements)

  const bf16* Asrc = A + (size_t)(m0 + w * 32 + rl) * DMODEL + csw;
  const bf16* Wsrc = W + (size_t)(n0 + w * 32 + rl) * DMODEL + csw;
  bf16* Adst = &Al[(w * 4) * 512];
  bf16* Bdst = &Bl[(w * 4) * 512];

  f32x4 acc[4][4];
#pragma unroll
  for (int i = 0; i < 4; i++)
#pragma unroll
    for (int j = 0; j < 4; j++) acc[i][j] = f32x4{0.f, 0.f, 0.f, 0.f};

  for (int k0 = 0; k0 < DMODEL; k0 += 64) {
    __syncthreads();
#pragma unroll
    for (int i = 0; i < 4; i++) {
      gload16(Asrc + k0 + (size_t)i * 8 * DMODEL, Adst + i * 512);
      gload16(Wsrc + k0 + (size_t)i * 8 * DMODEL, Bdst + i * 512);
    }
    __syncthreads();

    bf16x8 afr[4][2], bfr[4][2];
#pragma unroll
    for (int i = 0; i < 4; i++) {
      afr[i][0] = *reinterpret_cast<const bf16x8*>(&Al[sidx(wr + i * 16 + lrow, lko)]);
      afr[i][1] = *reinterpret_cast<const bf16x8*>(&Al[sidx(wr + i * 16 + lrow, 32 + lko)]);
      bfr[i][0] = *reinterpret_cast<const bf16x8*>(&Bl[sidx(wc + i * 16 + lrow, lko)]);
      bfr[i][1] = *reinterpret_cast<const bf16x8*>(&Bl[sidx(wc + i * 16 + lrow, 32 + lko)]);
    }
#pragma unroll
    for (int i = 0; i < 4; i++)
#pragma unroll
      for (int j = 0; j < 4; j++) {
        acc[i][j] = mfma16(afr[i][0], bfr[j][0], acc[i][j]);
        acc[i][j] = mfma16(afr[i][1], bfr[j][1], acc[i][j]);
      }
  }

  int rbase = lg * 4;
#pragma unroll
  for (int i = 0; i < 4; i++) {
    int row0 = m0 + wr + i * 16 + rbase;
#pragma unroll
    for (int j = 0; j < 4; j++) {
      int col = n0 + wc + j * 16 + lrow;
      int which = col >> 9, c2 = col & 511, hh = c2 >> 6, dd = c2 & 63;
      float bi = bias[col];
      if (which == 2) {
        // V^T: [bh][d][n]; 4 consecutive rows -> contiguous n, one 8B store
        int bb = row0 >> 10, nn = row0 & 1023;
        bf16x4 pack;
#pragma unroll
        for (int r = 0; r < 4; r++) pack[r] = (bf16)(acc[i][j][r] + bi);
        *reinterpret_cast<bf16x4*>(
            &ov[(((size_t)bb * N_HEADS + hh) * D_HEAD + dd) * N_SEQ + nn]) = pack;
      } else {
        bf16* dst = which == 0 ? oq : okk;
        float scl = which == 0 ? QSCALE : 1.0f;
#pragma unroll
        for (int r = 0; r < 4; r++) {
          int gm = row0 + r;
          int bb = gm >> 10, nn = gm & 1023;
          dst[(((size_t)bb * N_HEADS + hh) * N_SEQ + nn) * D_HEAD + dd] =
              (bf16)((acc[i][j][r] + bi) * scl);
        }
      }
    }
  }
}

// ---- bf16 MFMA GEMM (out-proj, mode-1 only): h = acc + bias + x, bf16 ----
__global__ __launch_bounds__(256) void k_gemm(const bf16* __restrict__ A,
    const bf16* __restrict__ W, int ncols,
    const float* __restrict__ bias, const float* __restrict__ xres,
    bf16* __restrict__ oh) {
  __shared__ bf16 Al[128 * 64];
  __shared__ bf16 Bl[128 * 64];
  int nbx = ncols >> 7;
  int cpx = gridDim.x >> 3;
  int wid = (blockIdx.x & 7) * cpx + (blockIdx.x >> 3);
  int bx = wid % nbx, by = wid / nbx;
  int m0 = by << 7, n0 = bx << 7;
  int tid = threadIdx.x, lane = tid & 63, w = tid >> 6;
  int wr = (w >> 1) << 6, wc = (w & 1) << 6;
  int lrow = lane & 15, lg = lane >> 4, lko = lg * 8;
  int rl = lane >> 3;
  int csw = ((lane & 7) ^ rl) << 3;

  const bf16* Asrc = A + (size_t)(m0 + w * 32 + rl) * DMODEL + csw;
  const bf16* Wsrc = W + (size_t)(n0 + w * 32 + rl) * DMODEL + csw;
  bf16* Adst = &Al[(w * 4) * 512];
  bf16* Bdst = &Bl[(w * 4) * 512];

  f32x4 acc[4][4];
#pragma unroll
  for (int i = 0; i < 4; i++)
#pragma unroll
    for (int j = 0; j < 4; j++) acc[i][j] = f32x4{0.f, 0.f, 0.f, 0.f};

  for (int k0 = 0; k0 < DMODEL; k0 += 64) {
    __syncthreads();
#pragma unroll
    for (int i = 0; i < 4; i++) {
      gload16(Asrc + k0 + (size_t)i * 8 * DMODEL, Adst + i * 512);
      gload16(Wsrc + k0 + (size_t)i * 8 * DMODEL, Bdst + i * 512);
    }
    __syncthreads();

    bf16x8 afr[4][2], bfr[4][2];
#pragma unroll
    for (int i = 0; i < 4; i++) {
      afr[i][0] = *reinterpret_cast<const bf16x8*>(&Al[sidx(wr + i * 16 + lrow, lko)]);
      afr[i][1] = *reinterpret_cast<const bf16x8*>(&Al[sidx(wr + i * 16 + lrow, 32 + lko)]);
      bfr[i][0] = *reinterpret_cast<const bf16x8*>(&Bl[sidx(wc + i * 16 + lrow, lko)]);
      bfr[i][1] = *reinterpret_cast<const bf16x8*>(&Bl[sidx(wc + i * 16 + lrow, 32 + lko)]);
    }
#pragma unroll
    for (int i = 0; i < 4; i++)
#pragma unroll
      for (int j = 0; j < 4; j++) {
        acc[i][j] = mfma16(afr[i][0], bfr[j][0], acc[i][j]);
        acc[i][j] = mfma16(afr[i][1], bfr[j][1], acc[i][j]);
      }
  }

  int rbase = lg * 4;
#pragma unroll
  for (int i = 0; i < 4; i++) {
    int row0 = m0 + wr + i * 16 + rbase;
#pragma unroll
    for (int j = 0; j < 4; j++) {
      int col = n0 + wc + j * 16 + lrow;
      float bi = bias[col];
#pragma unroll
      for (int r = 0; r < 4; r++) {
        int gm = row0 + r;
        float y = acc[i][j][r] + bi + xres[(size_t)gm * DMODEL + col];
        oh[(size_t)gm * DMODEL + col] = (bf16)y;
      }
    }
  }
}

// ---- masked attention: frozen round-10/15 equilibrium kernel ----
// (structure proven stable at ~42.8us across rounds 10/15; counted vmcnt
// retained -- equal perf, keeps prefetch in flight across barriers)
__global__ __launch_bounds__(256, 4) void k_attn(const bf16* __restrict__ Qb,
    const bf16* __restrict__ Kb, const bf16* __restrict__ Vtg,
    const u64* __restrict__ maskb, bf16* __restrict__ attn_out) {
  __shared__ bf16 Kl[2][64 * 64];
  __shared__ bf16 Vt[2][64 * 64];

  int bid = blockIdx.x;
  int work = ((bid & 7) << 7) | (bid >> 3);  // XCD swizzle (1024 = 8*128, bijective)
  int bh = work >> 4, qb = work & 15;
  int bb = bh >> 3, hh = bh & 7;
  int tid = threadIdx.x, lane = tid & 63, w = tid >> 6;
  int lrow = lane & 15, lg = lane >> 4;
  int rl = lane >> 3;
  int csw = ((lane & 7) ^ rl) << 3;
  int q0w = qb * 64 + w * 16;

  const bf16* Qh = Qb + (size_t)bh * N_SEQ * D_HEAD;
  const bf16* Kh = Kb + (size_t)bh * N_SEQ * D_HEAD;
  const bf16* Vh = Vtg + (size_t)bh * D_HEAD * N_SEQ;  // [d][n]
  const u32* m32 = (const u32*)(maskb + (size_t)bb * N_SEQ * 16);

  const bf16* Ksrc = Kh + (size_t)(w * 16 + rl) * D_HEAD + csw;
  const bf16* Vsrc = Vh + (size_t)(w * 16 + rl) * N_SEQ + csw;

  bf16x8 qf0 = *reinterpret_cast<const bf16x8*>(&Qh[(q0w + lrow) * 64 + lg * 8]);
  bf16x8 qf1 = *reinterpret_cast<const bf16x8*>(&Qh[(q0w + lrow) * 64 + 32 + lg * 8]);

  f32x4 o[4];   // o[dblk][r] = O[q=lrow][d=dblk*16+lg*4+r]
#pragma unroll
  for (int d = 0; d < 4; d++) o[d] = f32x4{0.f, 0.f, 0.f, 0.f};
  float ls = 0.f;

#define STAGE(buf, kt0)                                                     \
  {                                                                         \
    _Pragma("unroll") for (int i = 0; i < 2; i++) {                         \
      gload16(Ksrc + (size_t)(kt0) * 64 + i * 512, &Kl[buf][(w * 2 + i) * 512]); \
      gload16(Vsrc + (size_t)i * 8192 + (kt0), &Vt[buf][(w * 2 + i) * 512]);     \
    }                                                                       \
  }

  STAGE(0, 0);

  for (int kt = 0; kt < 16; kt++) {
    int cur = kt & 1;
    int kt0 = kt << 6;
    int midx = ((q0w + lrow) * 16 + kt) * 2;
    u32 mlo = m32[midx], mhi = m32[midx + 1];

    if (kt < 15) STAGE(cur ^ 1, kt0 + 64);

    __builtin_amdgcn_sched_barrier(0);
    if (kt < 15) { asm volatile("s_waitcnt vmcnt(6)" ::: "memory"); }
    else         { asm volatile("s_waitcnt vmcnt(2)" ::: "memory"); }
    __builtin_amdgcn_sched_barrier(0);
    __builtin_amdgcn_s_barrier();
    __builtin_amdgcn_sched_barrier(0);

    f32x4 sc[4];
#pragma unroll
    for (int t = 0; t < 4; t++) {
      bf16x8 kf0 = *reinterpret_cast<const bf16x8*>(&Kl[cur][sidx(t * 16 + lrow, lg * 8)]);
      bf16x8 kf1 = *reinterpret_cast<const bf16x8*>(&Kl[cur][sidx(t * 16 + lrow, 32 + lg * 8)]);
      sc[t] = f32x4{0.f, 0.f, 0.f, 0.f};
      __builtin_amdgcn_s_setprio(1);
      sc[t] = mfma16(kf0, qf0, sc[t]);
      sc[t] = mfma16(kf1, qf1, sc[t]);
      __builtin_amdgcn_s_setprio(0);
    }

    bf16x8 pa[2];
#pragma unroll
    for (int m = 0; m < 2; m++) {
      u32 mw = m == 0 ? mlo : mhi;
#pragma unroll
      for (int j = 0; j < 8; j++) {
        int sh = ((j >> 2) << 4) + lg * 4 + (j & 3);
        int t = 2 * m + (j >> 2), r = j & 3;
        bool bit = (mw >> sh) & 1u;
        float pv = bit ? exp2f(sc[t][r]) : 0.f;
        ls += pv;
        pa[m][j] = (bf16)pv;
      }
    }

#pragma unroll
    for (int d = 0; d < 4; d++) {
#pragma unroll
      for (int m = 0; m < 2; m++) {
        bf16x4 va = *reinterpret_cast<const bf16x4*>(
            &Vt[cur][sidx(d * 16 + lrow, m * 32 + lg * 4)]);
        bf16x4 vb = *reinterpret_cast<const bf16x4*>(
            &Vt[cur][sidx(d * 16 + lrow, m * 32 + 16 + lg * 4)]);
        bf16x8 vf = {va[0], va[1], va[2], va[3], vb[0], vb[1], vb[2], vb[3]};
        __builtin_amdgcn_s_setprio(1);
        o[d] = mfma16(vf, pa[m], o[d]);
        __builtin_amdgcn_s_setprio(0);
      }
    }

    __builtin_amdgcn_sched_barrier(0);
    asm volatile("s_waitcnt lgkmcnt(0)" ::: "memory");
    __builtin_amdgcn_s_barrier();
    __builtin_amdgcn_sched_barrier(0);
  }

  ls += __shfl_xor(ls, 16);
  ls += __shfl_xor(ls, 32);
  float inv = 1.f / ls;  // l > 0 via self-loop

  int gq = q0w + lrow;
#pragma unroll
  for (int d = 0; d < 4; d++) {
    bf16x4 pk;
#pragma unroll
    for (int r = 0; r < 4; r++) pk[r] = (bf16)(o[d][r] * inv);
    *reinterpret_cast<bf16x4*>(
        &attn_out[((size_t)(bb * N_SEQ + gq)) * DMODEL + hh * 64 + d * 16 + lg * 4]) = pk;
  }
#undef STAGE
}

// ---- row LayerNorm: one block per row, bf16 h input ----
__global__ __launch_bounds__(256) void k_ln(const bf16* __restrict__ hb,
    const float* __restrict__ gamma, const float* __restrict__ beta,
    float* __restrict__ out) {
  int row = blockIdx.x, tid = threadIdx.x;
  bf16x2 v2 = *reinterpret_cast<const bf16x2*>(hb + (size_t)row * DMODEL + tid * 2);
  float vx = (float)v2[0], vy = (float)v2[1];
  float s = vx + vy, ss = vx * vx + vy * vy;
#pragma unroll
  for (int off = 1; off < 64; off <<= 1) {
    s += __shfl_xor(s, off);
    ss += __shfl_xor(ss, off);
  }
  __shared__ float as_[4], ass_[4];
  int w = tid >> 6;
  if ((tid & 63) == 0) { as_[w] = s; ass_[w] = ss; }
  __syncthreads();
  s = as_[0] + as_[1] + as_[2] + as_[3];
  ss = ass_[0] + ass_[1] + ass_[2] + ass_[3];
  float mu = s * (1.f / 512.f);
  float var = ss * (1.f / 512.f) - mu * mu;
  float rstd = rsqrtf(var + 1e-5f);
  float2 g = reinterpret_cast<const float2*>(gamma)[tid];
  float2 bt = reinterpret_cast<const float2*>(beta)[tid];
  float2 o;
  o.x = (vx - mu) * rstd * g.x + bt.x;
  o.y = (vy - mu) * rstd * g.y + bt.y;
  reinterpret_cast<float2*>(out + (size_t)row * DMODEL)[tid] = o;
}

extern "C" void kernel_launch(void* const* d_in, const int* in_sizes, int n_in,
                              void* d_out, int out_size, void* d_ws, size_t ws_size,
                              hipStream_t stream) {
  const float* x     = (const float*)d_in[0];
  const float* adj   = (const float*)d_in[1];
  const float* Wq    = (const float*)d_in[2];
  const float* bq    = (const float*)d_in[3];
  const float* Wk    = (const float*)d_in[4];
  const float* bk    = (const float*)d_in[5];
  const float* Wv    = (const float*)d_in[6];
  const float* bv    = (const float*)d_in[7];
  const float* Wo    = (const float*)d_in[8];
  const float* bo    = (const float*)d_in[9];
  const float* gamma = (const float*)d_in[10];
  const float* beta  = (const float*)d_in[11];

  char* ws = (char*)d_ws;
  bf16* xb    = (bf16*)(ws + OFF_XB);
  bf16* wqkv  = (bf16*)(ws + OFF_WQKV);
  bf16* wo    = (bf16*)(ws + OFF_WO);
  float* bqkv = (float*)(ws + OFF_BQKV);
  bf16* Qb    = (bf16*)(ws + OFF_Q);
  bf16* Kb    = (bf16*)(ws + OFF_K);
  bf16* Vb    = (bf16*)(ws + OFF_V);   // holds V^T
  u64* maskb  = (u64*)(ws + OFF_MASK);
  bf16* attn  = xb;                    // x_bf16 dead after QKV GEMM
  bf16* hb    = (bf16*)(ws + OFF_Q);   // Q/K dead after attention; h in bf16
  float* out  = (float*)d_out;

  // 1. prep: x cvt + wqkv + bias (adj/wo deferred into hetero GEMM-1)
  k_prep<<<dim3(PREP_X_BLK + PREP_W_BLK), dim3(256), 0, stream>>>(
      x, Wq, Wk, Wv, bq, bk, bv, xb, wqkv, bqkv);

  // 2. hetero: QKV GEMM + mask build + wo pack (mask HBM hides under MFMA)
  k_gemm1f<<<dim3(G1_GEMM + G1_MASK + G1_WO), dim3(256), 0, stream>>>(
      xb, wqkv, bqkv, Qb, Kb, Vb, adj, Wo, wo, maskb);

  // 3. masked attention (frozen equilibrium kernel)
  k_attn<<<dim3(1024), dim3(256), 0, stream>>>(Qb, Kb, Vb, maskb, attn);

  // 4. output projection + bias + residual -> h bf16 (M=8192, N=512)
  k_gemm<<<dim3((M_ROWS / 128) * (512 / 128)), dim3(256), 0, stream>>>(
      attn, wo, 512, bo, x, hb);

  // 5. LayerNorm
  k_ln<<<dim3(M_ROWS), dim3(256), 0, stream>>>(hb, gamma, beta, out);
}

// Round 17
// 102.324 us; speedup vs baseline: 1.2068x; 1.2068x over previous
//
#include <hip/hip_runtime.h>

typedef __bf16 bf16;
typedef bf16 bf16x8 __attribute__((ext_vector_type(8)));
typedef bf16 bf16x4 __attribute__((ext_vector_type(4)));
typedef bf16 bf16x2 __attribute__((ext_vector_type(2)));
typedef float f32x4 __attribute__((ext_vector_type(4)));
typedef unsigned long long u64;
typedef unsigned int u32;

#define B_SZ 8
#define N_SEQ 1024
#define DMODEL 512
#define N_HEADS 8
#define D_HEAD 64
#define M_ROWS 8192   // B_SZ * N_SEQ

// Q pre-scale: 1/sqrt(64) * log2(e), so softmax uses exp2 directly
#define QSCALE 0.18033688011112042f

// ---- workspace layout (bytes) ----
static constexpr size_t OFF_XB   = 0;                                   // bf16 [8192][512]; reused as attn_out later
static constexpr size_t OFF_WQKV = (size_t)M_ROWS * DMODEL * 2;         // bf16 [1536][512]
static constexpr size_t OFF_WO   = OFF_WQKV + (size_t)1536 * 512 * 2;   // bf16 [512][512]
static constexpr size_t OFF_BQKV = OFF_WO + (size_t)512 * 512 * 2;      // f32  [1536]
static constexpr size_t OFF_Q    = OFF_BQKV + 1536 * 4;                 // bf16 [64][1024][64]; later reused as h bf16
static constexpr size_t OFF_K    = OFF_Q + (size_t)64 * 1024 * 64 * 2;
static constexpr size_t OFF_V    = OFF_K + (size_t)64 * 1024 * 64 * 2;  // V^T: bf16 [64 bh][64 d][1024 n]
static constexpr size_t OFF_MASK = OFF_V + (size_t)64 * 1024 * 64 * 2;  // u64 [8][1024][16]

// k_prep block partition (256 threads each)
#define PREP_X_BLK 4096    // 8192*512 elems / 4-per-thread / 256
#define PREP_W_BLK 4102    // (1536*512 + 512*512 + 1536) / 256
#define PREP_M_BLK 4096    // mask: grid-strided, 8 iters each (G11)
#define PREP_M_ITER 8

__device__ __forceinline__ f32x4 mfma16(bf16x8 a, bf16x8 b, f32x4 c) {
  return __builtin_amdgcn_mfma_f32_16x16x32_bf16(a, b, c, 0, 0, 0);
}

// XOR swizzle for [R][64] bf16 LDS tiles (row = 128B) -- guide G4 / T2.
__device__ __forceinline__ int sidx(int row, int col) {
  return (row << 6) + (col ^ ((row & 7) << 3));
}

// async global->LDS, 16B per lane; LDS dest = wave-uniform base + lane*16.
__device__ __forceinline__ void gload16(const void* g, void* l) {
  __builtin_amdgcn_global_load_lds(
      (const __attribute__((address_space(1))) void*)g,
      (__attribute__((address_space(3))) void*)l, 16, 0, 0);
}

// ---- merged prep: cvt x, pack weights/biases, build mask bits ----
__global__ void k_prep(const float* __restrict__ x, const float* __restrict__ adj,
                       const float* __restrict__ Wq, const float* __restrict__ Wk,
                       const float* __restrict__ Wv, const float* __restrict__ Wo,
                       const float* __restrict__ bq, const float* __restrict__ bk,
                       const float* __restrict__ bv,
                       bf16* __restrict__ xb, bf16* __restrict__ wqkv,
                       bf16* __restrict__ wo, float* __restrict__ bqkv,
                       u64* __restrict__ maskb) {
  int b = blockIdx.x;
  if (b < PREP_X_BLK) {                 // x fp32 -> bf16, 4/thread
    int i = b * 256 + threadIdx.x;
    float4 v = reinterpret_cast<const float4*>(x)[i];
    bf16x4 o = { (bf16)v.x, (bf16)v.y, (bf16)v.z, (bf16)v.w };
    *reinterpret_cast<bf16x4*>(xb + (size_t)i * 4) = o;
  } else if (b < PREP_X_BLK + PREP_W_BLK) {  // weights/biases
    int tid = (b - PREP_X_BLK) * 256 + threadIdx.x;
    if (tid < 1536 * 512) {
      int row = tid >> 9;
      const float* Wsrc = row < 512 ? Wq : row < 1024 ? Wk : Wv;
      wqkv[tid] = (bf16)Wsrc[((row & 511) << 9) | (tid & 511)];
    } else if (tid < 1536 * 512 + 512 * 512) {
      int t = tid - 1536 * 512;
      wo[t] = (bf16)Wo[t];
    } else if (tid < 1536 * 512 + 512 * 512 + 1536) {
      int t = tid - (1536 * 512 + 512 * 512);
      bqkv[t] = t < 512 ? bq[t] : t < 1024 ? bk[t - 512] : bv[t - 1024];
    }
  } else {                              // adjacency -> mask bits, grid-strided
    int b0 = b - (PREP_X_BLK + PREP_W_BLK);
#pragma unroll
    for (int it = 0; it < PREP_M_ITER; it++) {
      int idx = (b0 + it * PREP_M_BLK) * 256 + threadIdx.x;
      int q = (idx >> 10) & 1023, k = idx & 1023;
      bool pred = (adj[idx] > 0.f) || (q == k);
      u64 bal = __ballot(pred);
      if ((threadIdx.x & 63) == 0) maskb[idx >> 6] = bal;
    }
  }
}

// ---- bf16 MFMA GEMM, m97 structure + XCD-aware block swizzle (T1) ----
// mode 0: scatter Q (pre-scaled QSCALE) / K bf16 into [b,h,n,d], V into V^T [b,h,d,n]
// mode 1: h = acc + bias + x, stored bf16
__global__ __launch_bounds__(256) void k_gemm(const bf16* __restrict__ A,
    const bf16* __restrict__ W, int ncols, int mode,
    const float* __restrict__ bias, const float* __restrict__ xres,
    bf16* __restrict__ oq, bf16* __restrict__ okk, bf16* __restrict__ ov,
    bf16* __restrict__ oh) {
  __shared__ bf16 Al[128 * 64];
  __shared__ bf16 Bl[128 * 64];
  int nbx = ncols >> 7;
  int cpx = gridDim.x >> 3;
  int wid = (blockIdx.x & 7) * cpx + (blockIdx.x >> 3);
  int bx = wid % nbx, by = wid / nbx;
  int m0 = by << 7, n0 = bx << 7;
  int tid = threadIdx.x, lane = tid & 63, w = tid >> 6;
  int wr = (w >> 1) << 6, wc = (w & 1) << 6;
  int lrow = lane & 15, lg = lane >> 4, lko = lg * 8;
  int rl = lane >> 3;                   // row-in-group 0..7
  int csw = ((lane & 7) ^ rl) << 3;     // pre-swizzled col (elements)

  const bf16* Asrc = A + (size_t)(m0 + w * 32 + rl) * DMODEL + csw;
  const bf16* Wsrc = W + (size_t)(n0 + w * 32 + rl) * DMODEL + csw;
  bf16* Adst = &Al[(w * 4) * 512];
  bf16* Bdst = &Bl[(w * 4) * 512];

  f32x4 acc[4][4];
#pragma unroll
  for (int i = 0; i < 4; i++)
#pragma unroll
    for (int j = 0; j < 4; j++) acc[i][j] = f32x4{0.f, 0.f, 0.f, 0.f};

  for (int k0 = 0; k0 < DMODEL; k0 += 64) {
    __syncthreads();
#pragma unroll
    for (int i = 0; i < 4; i++) {
      gload16(Asrc + k0 + (size_t)i * 8 * DMODEL, Adst + i * 512);
      gload16(Wsrc + k0 + (size_t)i * 8 * DMODEL, Bdst + i * 512);
    }
    __syncthreads();

    bf16x8 afr[4][2], bfr[4][2];
#pragma unroll
    for (int i = 0; i < 4; i++) {
      afr[i][0] = *reinterpret_cast<const bf16x8*>(&Al[sidx(wr + i * 16 + lrow, lko)]);
      afr[i][1] = *reinterpret_cast<const bf16x8*>(&Al[sidx(wr + i * 16 + lrow, 32 + lko)]);
      bfr[i][0] = *reinterpret_cast<const bf16x8*>(&Bl[sidx(wc + i * 16 + lrow, lko)]);
      bfr[i][1] = *reinterpret_cast<const bf16x8*>(&Bl[sidx(wc + i * 16 + lrow, 32 + lko)]);
    }
#pragma unroll
    for (int i = 0; i < 4; i++)
#pragma unroll
      for (int j = 0; j < 4; j++) {
        acc[i][j] = mfma16(afr[i][0], bfr[j][0], acc[i][j]);
        acc[i][j] = mfma16(afr[i][1], bfr[j][1], acc[i][j]);
      }
  }

  int rbase = lg * 4;
  if (mode == 0) {
#pragma unroll
    for (int i = 0; i < 4; i++) {
      int row0 = m0 + wr + i * 16 + rbase;
#pragma unroll
      for (int j = 0; j < 4; j++) {
        int col = n0 + wc + j * 16 + lrow;
        int which = col >> 9, c2 = col & 511, hh = c2 >> 6, dd = c2 & 63;
        float bi = bias[col];
        if (which == 2) {
          int bb = row0 >> 10, nn = row0 & 1023;
          bf16x4 pack;
#pragma unroll
          for (int r = 0; r < 4; r++) pack[r] = (bf16)(acc[i][j][r] + bi);
          *reinterpret_cast<bf16x4*>(
              &ov[(((size_t)bb * N_HEADS + hh) * D_HEAD + dd) * N_SEQ + nn]) = pack;
        } else {
          bf16* dst = which == 0 ? oq : okk;
          float scl = which == 0 ? QSCALE : 1.0f;
#pragma unroll
          for (int r = 0; r < 4; r++) {
            int gm = row0 + r;
            int bb = gm >> 10, nn = gm & 1023;
            dst[(((size_t)bb * N_HEADS + hh) * N_SEQ + nn) * D_HEAD + dd] =
                (bf16)((acc[i][j][r] + bi) * scl);
          }
        }
      }
    }
  } else {
#pragma unroll
    for (int i = 0; i < 4; i++) {
      int row0 = m0 + wr + i * 16 + rbase;
#pragma unroll
      for (int j = 0; j < 4; j++) {
        int col = n0 + wc + j * 16 + lrow;
        float bi = bias[col];
#pragma unroll
        for (int r = 0; r < 4; r++) {
          int gm = row0 + r;
          float y = acc[i][j][r] + bi + xres[(size_t)gm * DMODEL + col];
          oh[(size_t)gm * DMODEL + col] = (bf16)y;
        }
      }
    }
  }
}

// ---- masked attention: frozen round-10/15 equilibrium kernel ----
__global__ __launch_bounds__(256, 4) void k_attn(const bf16* __restrict__ Qb,
    const bf16* __restrict__ Kb, const bf16* __restrict__ Vtg,
    const u64* __restrict__ maskb, bf16* __restrict__ attn_out) {
  __shared__ bf16 Kl[2][64 * 64];
  __shared__ bf16 Vt[2][64 * 64];

  int bid = blockIdx.x;
  int work = ((bid & 7) << 7) | (bid >> 3);  // XCD swizzle (1024 = 8*128, bijective)
  int bh = work >> 4, qb = work & 15;
  int bb = bh >> 3, hh = bh & 7;
  int tid = threadIdx.x, lane = tid & 63, w = tid >> 6;
  int lrow = lane & 15, lg = lane >> 4;
  int rl = lane >> 3;
  int csw = ((lane & 7) ^ rl) << 3;
  int q0w = qb * 64 + w * 16;

  const bf16* Qh = Qb + (size_t)bh * N_SEQ * D_HEAD;
  const bf16* Kh = Kb + (size_t)bh * N_SEQ * D_HEAD;
  const bf16* Vh = Vtg + (size_t)bh * D_HEAD * N_SEQ;  // [d][n]
  const u32* m32 = (const u32*)(maskb + (size_t)bb * N_SEQ * 16);

  const bf16* Ksrc = Kh + (size_t)(w * 16 + rl) * D_HEAD + csw;
  const bf16* Vsrc = Vh + (size_t)(w * 16 + rl) * N_SEQ + csw;

  bf16x8 qf0 = *reinterpret_cast<const bf16x8*>(&Qh[(q0w + lrow) * 64 + lg * 8]);
  bf16x8 qf1 = *reinterpret_cast<const bf16x8*>(&Qh[(q0w + lrow) * 64 + 32 + lg * 8]);

  f32x4 o[4];   // o[dblk][r] = O[q=lrow][d=dblk*16+lg*4+r]
#pragma unroll
  for (int d = 0; d < 4; d++) o[d] = f32x4{0.f, 0.f, 0.f, 0.f};
  float ls = 0.f;

#define STAGE(buf, kt0)                                                     \
  {                                                                         \
    _Pragma("unroll") for (int i = 0; i < 2; i++) {                         \
      gload16(Ksrc + (size_t)(kt0) * 64 + i * 512, &Kl[buf][(w * 2 + i) * 512]); \
      gload16(Vsrc + (size_t)i * 8192 + (kt0), &Vt[buf][(w * 2 + i) * 512]);     \
    }                                                                       \
  }

  STAGE(0, 0);

  for (int kt = 0; kt < 16; kt++) {
    int cur = kt & 1;
    int kt0 = kt << 6;
    int midx = ((q0w + lrow) * 16 + kt) * 2;
    u32 mlo = m32[midx], mhi = m32[midx + 1];

    if (kt < 15) STAGE(cur ^ 1, kt0 + 64);

    __builtin_amdgcn_sched_barrier(0);
    if (kt < 15) { asm volatile("s_waitcnt vmcnt(6)" ::: "memory"); }
    else         { asm volatile("s_waitcnt vmcnt(2)" ::: "memory"); }
    __builtin_amdgcn_sched_barrier(0);
    __builtin_amdgcn_s_barrier();
    __builtin_amdgcn_sched_barrier(0);

    f32x4 sc[4];
#pragma unroll
    for (int t = 0; t < 4; t++) {
      bf16x8 kf0 = *reinterpret_cast<const bf16x8*>(&Kl[cur][sidx(t * 16 + lrow, lg * 8)]);
      bf16x8 kf1 = *reinterpret_cast<const bf16x8*>(&Kl[cur][sidx(t * 16 + lrow, 32 + lg * 8)]);
      sc[t] = f32x4{0.f, 0.f, 0.f, 0.f};
      __builtin_amdgcn_s_setprio(1);
      sc[t] = mfma16(kf0, qf0, sc[t]);
      sc[t] = mfma16(kf1, qf1, sc[t]);
      __builtin_amdgcn_s_setprio(0);
    }

    bf16x8 pa[2];
#pragma unroll
    for (int m = 0; m < 2; m++) {
      u32 mw = m == 0 ? mlo : mhi;
#pragma unroll
      for (int j = 0; j < 8; j++) {
        int sh = ((j >> 2) << 4) + lg * 4 + (j & 3);
        int t = 2 * m + (j >> 2), r = j & 3;
        bool bit = (mw >> sh) & 1u;
        float pv = bit ? exp2f(sc[t][r]) : 0.f;
        ls += pv;
        pa[m][j] = (bf16)pv;
      }
    }

#pragma unroll
    for (int d = 0; d < 4; d++) {
#pragma unroll
      for (int m = 0; m < 2; m++) {
        bf16x4 va = *reinterpret_cast<const bf16x4*>(
            &Vt[cur][sidx(d * 16 + lrow, m * 32 + lg * 4)]);
        bf16x4 vb = *reinterpret_cast<const bf16x4*>(
            &Vt[cur][sidx(d * 16 + lrow, m * 32 + 16 + lg * 4)]);
        bf16x8 vf = {va[0], va[1], va[2], va[3], vb[0], vb[1], vb[2], vb[3]};
        __builtin_amdgcn_s_setprio(1);
        o[d] = mfma16(vf, pa[m], o[d]);
        __builtin_amdgcn_s_setprio(0);
      }
    }

    __builtin_amdgcn_sched_barrier(0);
    asm volatile("s_waitcnt lgkmcnt(0)" ::: "memory");
    __builtin_amdgcn_s_barrier();
    __builtin_amdgcn_sched_barrier(0);
  }

  ls += __shfl_xor(ls, 16);
  ls += __shfl_xor(ls, 32);
  float inv = 1.f / ls;  // l > 0 via self-loop

  int gq = q0w + lrow;
#pragma unroll
  for (int d = 0; d < 4; d++) {
    bf16x4 pk;
#pragma unroll
    for (int r = 0; r < 4; r++) pk[r] = (bf16)(o[d][r] * inv);
    *reinterpret_cast<bf16x4*>(
        &attn_out[((size_t)(bb * N_SEQ + gq)) * DMODEL + hh * 64 + d * 16 + lg * 4]) = pk;
  }
#undef STAGE
}

// ---- row LayerNorm: one block per row, bf16 h input ----
__global__ __launch_bounds__(256) void k_ln(const bf16* __restrict__ hb,
    const float* __restrict__ gamma, const float* __restrict__ beta,
    float* __restrict__ out) {
  int row = blockIdx.x, tid = threadIdx.x;
  bf16x2 v2 = *reinterpret_cast<const bf16x2*>(hb + (size_t)row * DMODEL + tid * 2);
  float vx = (float)v2[0], vy = (float)v2[1];
  float s = vx + vy, ss = vx * vx + vy * vy;
#pragma unroll
  for (int off = 1; off < 64; off <<= 1) {
    s += __shfl_xor(s, off);
    ss += __shfl_xor(ss, off);
  }
  __shared__ float as_[4], ass_[4];
  int w = tid >> 6;
  if ((tid & 63) == 0) { as_[w] = s; ass_[w] = ss; }
  __syncthreads();
  s = as_[0] + as_[1] + as_[2] + as_[3];
  ss = ass_[0] + ass_[1] + ass_[2] + ass_[3];
  float mu = s * (1.f / 512.f);
  float var = ss * (1.f / 512.f) - mu * mu;
  float rstd = rsqrtf(var + 1e-5f);
  float2 g = reinterpret_cast<const float2*>(gamma)[tid];
  float2 bt = reinterpret_cast<const float2*>(beta)[tid];
  float2 o;
  o.x = (vx - mu) * rstd * g.x + bt.x;
  o.y = (vy - mu) * rstd * g.y + bt.y;
  reinterpret_cast<float2*>(out + (size_t)row * DMODEL)[tid] = o;
}

extern "C" void kernel_launch(void* const* d_in, const int* in_sizes, int n_in,
                              void* d_out, int out_size, void* d_ws, size_t ws_size,
                              hipStream_t stream) {
  const float* x     = (const float*)d_in[0];
  const float* adj   = (const float*)d_in[1];
  const float* Wq    = (const float*)d_in[2];
  const float* bq    = (const float*)d_in[3];
  const float* Wk    = (const float*)d_in[4];
  const float* bk    = (const float*)d_in[5];
  const float* Wv    = (const float*)d_in[6];
  const float* bv    = (const float*)d_in[7];
  const float* Wo    = (const float*)d_in[8];
  const float* bo    = (const float*)d_in[9];
  const float* gamma = (const float*)d_in[10];
  const float* beta  = (const float*)d_in[11];

  char* ws = (char*)d_ws;
  bf16* xb    = (bf16*)(ws + OFF_XB);
  bf16* wqkv  = (bf16*)(ws + OFF_WQKV);
  bf16* wo    = (bf16*)(ws + OFF_WO);
  float* bqkv = (float*)(ws + OFF_BQKV);
  bf16* Qb    = (bf16*)(ws + OFF_Q);
  bf16* Kb    = (bf16*)(ws + OFF_K);
  bf16* Vb    = (bf16*)(ws + OFF_V);   // holds V^T
  u64* maskb  = (u64*)(ws + OFF_MASK);
  bf16* attn  = xb;                    // x_bf16 dead after QKV GEMM
  bf16* hb    = (bf16*)(ws + OFF_Q);   // Q/K dead after attention; h in bf16
  float* out  = (float*)d_out;

  // 1. merged prep (x cvt + weight pack + grid-strided mask build)
  k_prep<<<dim3(PREP_X_BLK + PREP_W_BLK + PREP_M_BLK), dim3(256), 0, stream>>>(
      x, adj, Wq, Wk, Wv, Wo, bq, bk, bv, xb, wqkv, wo, bqkv, maskb);

  // 2. QKV projection (M=8192, N=1536), V stored transposed, Q pre-scaled
  k_gemm<<<dim3((M_ROWS / 128) * (1536 / 128)), dim3(256), 0, stream>>>(
      xb, wqkv, 1536, 0, bqkv, nullptr, Qb, Kb, Vb, nullptr);

  // 3. masked attention (frozen equilibrium kernel)
  k_attn<<<dim3(1024), dim3(256), 0, stream>>>(Qb, Kb, Vb, maskb, attn);

  // 4. output projection + bias + residual -> h bf16 (M=8192, N=512)
  k_gemm<<<dim3((M_ROWS / 128) * (512 / 128)), dim3(256), 0, stream>>>(
      attn, wo, 512, 1, bo, x, nullptr, nullptr, nullptr, hb);

  // 5. LayerNorm
  k_ln<<<dim3(M_ROWS), dim3(256), 0, stream>>>(hb, gamma, beta, out);
}

// Round 18
// 100.760 us; speedup vs baseline: 1.2255x; 1.0155x over previous
//
#include <hip/hip_runtime.h>

typedef __bf16 bf16;
typedef bf16 bf16x8 __attribute__((ext_vector_type(8)));
typedef bf16 bf16x4 __attribute__((ext_vector_type(4)));
typedef bf16 bf16x2 __attribute__((ext_vector_type(2)));
typedef float f32x4 __attribute__((ext_vector_type(4)));
typedef unsigned long long u64;
typedef unsigned int u32;

#define B_SZ 8
#define N_SEQ 1024
#define DMODEL 512
#define N_HEADS 8
#define D_HEAD 64
#define M_ROWS 8192   // B_SZ * N_SEQ

// Q pre-scale: 1/sqrt(64) * log2(e), so softmax uses exp2 directly
#define QSCALE 0.18033688011112042f

// ---- workspace layout (bytes) ----
static constexpr size_t OFF_XB   = 0;                                   // bf16 [8192][512]; reused as attn_out later
static constexpr size_t OFF_WQKV = (size_t)M_ROWS * DMODEL * 2;         // bf16 [1536][512]
static constexpr size_t OFF_WO   = OFF_WQKV + (size_t)1536 * 512 * 2;   // bf16 [512][512]
static constexpr size_t OFF_BQKV = OFF_WO + (size_t)512 * 512 * 2;      // f32  [1536]
static constexpr size_t OFF_Q    = OFF_BQKV + 1536 * 4;                 // bf16 [64][1024][64]; later reused as h bf16
static constexpr size_t OFF_K    = OFF_Q + (size_t)64 * 1024 * 64 * 2;
static constexpr size_t OFF_V    = OFF_K + (size_t)64 * 1024 * 64 * 2;  // V^T k-interleaved: [64 bh][64 d][1024 n']
static constexpr size_t OFF_MASK = OFF_V + (size_t)64 * 1024 * 64 * 2;  // u64 [8][1024][16]

// k_prep block partition (256 threads each)
#define PREP_X_BLK 4096    // 8192*512 elems / 4-per-thread / 256
#define PREP_W_BLK 4102    // (1536*512 + 512*512 + 1536) / 256
#define PREP_M_BLK 4096    // mask: grid-strided, 8 iters each (G11)
#define PREP_M_ITER 8

__device__ __forceinline__ f32x4 mfma16(bf16x8 a, bf16x8 b, f32x4 c) {
  return __builtin_amdgcn_mfma_f32_16x16x32_bf16(a, b, c, 0, 0, 0);
}

// XOR swizzle for [R][64] bf16 LDS tiles (row = 128B) -- guide G4 / T2.
__device__ __forceinline__ int sidx(int row, int col) {
  return (row << 6) + (col ^ ((row & 7) << 3));
}

// async global->LDS, 16B per lane; LDS dest = wave-uniform base + lane*16.
__device__ __forceinline__ void gload16(const void* g, void* l) {
  __builtin_amdgcn_global_load_lds(
      (const __attribute__((address_space(1))) void*)g,
      (__attribute__((address_space(3))) void*)l, 16, 0, 0);
}

// ---- merged prep: cvt x, pack weights/biases, build mask bits ----
__global__ void k_prep(const float* __restrict__ x, const float* __restrict__ adj,
                       const float* __restrict__ Wq, const float* __restrict__ Wk,
                       const float* __restrict__ Wv, const float* __restrict__ Wo,
                       const float* __restrict__ bq, const float* __restrict__ bk,
                       const float* __restrict__ bv,
                       bf16* __restrict__ xb, bf16* __restrict__ wqkv,
                       bf16* __restrict__ wo, float* __restrict__ bqkv,
                       u64* __restrict__ maskb) {
  int b = blockIdx.x;
  if (b < PREP_X_BLK) {                 // x fp32 -> bf16, 4/thread
    int i = b * 256 + threadIdx.x;
    float4 v = reinterpret_cast<const float4*>(x)[i];
    bf16x4 o = { (bf16)v.x, (bf16)v.y, (bf16)v.z, (bf16)v.w };
    *reinterpret_cast<bf16x4*>(xb + (size_t)i * 4) = o;
  } else if (b < PREP_X_BLK + PREP_W_BLK) {  // weights/biases
    int tid = (b - PREP_X_BLK) * 256 + threadIdx.x;
    if (tid < 1536 * 512) {
      int row = tid >> 9;
      const float* Wsrc = row < 512 ? Wq : row < 1024 ? Wk : Wv;
      wqkv[tid] = (bf16)Wsrc[((row & 511) << 9) | (tid & 511)];
    } else if (tid < 1536 * 512 + 512 * 512) {
      int t = tid - 1536 * 512;
      wo[t] = (bf16)Wo[t];
    } else if (tid < 1536 * 512 + 512 * 512 + 1536) {
      int t = tid - (1536 * 512 + 512 * 512);
      bqkv[t] = t < 512 ? bq[t] : t < 1024 ? bk[t - 512] : bv[t - 1024];
    }
  } else {                              // adjacency -> mask bits, grid-strided
    int b0 = b - (PREP_X_BLK + PREP_W_BLK);
#pragma unroll
    for (int it = 0; it < PREP_M_ITER; it++) {
      int idx = (b0 + it * PREP_M_BLK) * 256 + threadIdx.x;
      int q = (idx >> 10) & 1023, k = idx & 1023;
      bool pred = (adj[idx] > 0.f) || (q == k);
      u64 bal = __ballot(pred);
      if ((threadIdx.x & 63) == 0) maskb[idx >> 6] = bal;
    }
  }
}

// ---- bf16 MFMA GEMM, m97 structure + XCD-aware block swizzle (T1) ----
// mode 0: scatter Q (pre-scaled QSCALE) / K bf16 into [b,h,n,d],
//         V into k-interleaved V^T [b,h,d,n'] where
//         n' = (n&~63)|(n&32)|((n&12)<<1)|((n&16)>>2)|(n&3)
//         (PV lane k-runs contiguous -> one ds_read_b128 per fragment)
// mode 1: h = acc + bias + x, stored bf16
__global__ __launch_bounds__(256) void k_gemm(const bf16* __restrict__ A,
    const bf16* __restrict__ W, int ncols, int mode,
    const float* __restrict__ bias, const float* __restrict__ xres,
    bf16* __restrict__ oq, bf16* __restrict__ okk, bf16* __restrict__ ov,
    bf16* __restrict__ oh) {
  __shared__ bf16 Al[128 * 64];
  __shared__ bf16 Bl[128 * 64];
  int nbx = ncols >> 7;
  int cpx = gridDim.x >> 3;
  int wid = (blockIdx.x & 7) * cpx + (blockIdx.x >> 3);
  int bx = wid % nbx, by = wid / nbx;
  int m0 = by << 7, n0 = bx << 7;
  int tid = threadIdx.x, lane = tid & 63, w = tid >> 6;
  int wr = (w >> 1) << 6, wc = (w & 1) << 6;
  int lrow = lane & 15, lg = lane >> 4, lko = lg * 8;
  int rl = lane >> 3;                   // row-in-group 0..7
  int csw = ((lane & 7) ^ rl) << 3;     // pre-swizzled col (elements)

  const bf16* Asrc = A + (size_t)(m0 + w * 32 + rl) * DMODEL + csw;
  const bf16* Wsrc = W + (size_t)(n0 + w * 32 + rl) * DMODEL + csw;
  bf16* Adst = &Al[(w * 4) * 512];
  bf16* Bdst = &Bl[(w * 4) * 512];

  f32x4 acc[4][4];
#pragma unroll
  for (int i = 0; i < 4; i++)
#pragma unroll
    for (int j = 0; j < 4; j++) acc[i][j] = f32x4{0.f, 0.f, 0.f, 0.f};

  for (int k0 = 0; k0 < DMODEL; k0 += 64) {
    __syncthreads();
#pragma unroll
    for (int i = 0; i < 4; i++) {
      gload16(Asrc + k0 + (size_t)i * 8 * DMODEL, Adst + i * 512);
      gload16(Wsrc + k0 + (size_t)i * 8 * DMODEL, Bdst + i * 512);
    }
    __syncthreads();

    bf16x8 afr[4][2], bfr[4][2];
#pragma unroll
    for (int i = 0; i < 4; i++) {
      afr[i][0] = *reinterpret_cast<const bf16x8*>(&Al[sidx(wr + i * 16 + lrow, lko)]);
      afr[i][1] = *reinterpret_cast<const bf16x8*>(&Al[sidx(wr + i * 16 + lrow, 32 + lko)]);
      bfr[i][0] = *reinterpret_cast<const bf16x8*>(&Bl[sidx(wc + i * 16 + lrow, lko)]);
      bfr[i][1] = *reinterpret_cast<const bf16x8*>(&Bl[sidx(wc + i * 16 + lrow, 32 + lko)]);
    }
#pragma unroll
    for (int i = 0; i < 4; i++)
#pragma unroll
      for (int j = 0; j < 4; j++) {
        acc[i][j] = mfma16(afr[i][0], bfr[j][0], acc[i][j]);
        acc[i][j] = mfma16(afr[i][1], bfr[j][1], acc[i][j]);
      }
  }

  int rbase = lg * 4;
  if (mode == 0) {
#pragma unroll
    for (int i = 0; i < 4; i++) {
      int row0 = m0 + wr + i * 16 + rbase;
#pragma unroll
      for (int j = 0; j < 4; j++) {
        int col = n0 + wc + j * 16 + lrow;
        int which = col >> 9, c2 = col & 511, hh = c2 >> 6, dd = c2 & 63;
        float bi = bias[col];
        if (which == 2) {
          int bb = row0 >> 10, nn = row0 & 1023;
          // k-interleave map (nn % 4 == 0 here): 4-run stays contiguous
          int n2 = (nn & ~63) | (nn & 32) | ((nn & 12) << 1) | ((nn & 16) >> 2);
          bf16x4 pack;
#pragma unroll
          for (int r = 0; r < 4; r++) pack[r] = (bf16)(acc[i][j][r] + bi);
          *reinterpret_cast<bf16x4*>(
              &ov[(((size_t)bb * N_HEADS + hh) * D_HEAD + dd) * N_SEQ + n2]) = pack;
        } else {
          bf16* dst = which == 0 ? oq : okk;
          float scl = which == 0 ? QSCALE : 1.0f;
#pragma unroll
          for (int r = 0; r < 4; r++) {
            int gm = row0 + r;
            int bb = gm >> 10, nn = gm & 1023;
            dst[(((size_t)bb * N_HEADS + hh) * N_SEQ + nn) * D_HEAD + dd] =
                (bf16)((acc[i][j][r] + bi) * scl);
          }
        }
      }
    }
  } else {
#pragma unroll
    for (int i = 0; i < 4; i++) {
      int row0 = m0 + wr + i * 16 + rbase;
#pragma unroll
      for (int j = 0; j < 4; j++) {
        int col = n0 + wc + j * 16 + lrow;
        float bi = bias[col];
#pragma unroll
        for (int r = 0; r < 4; r++) {
          int gm = row0 + r;
          float y = acc[i][j][r] + bi + xres[(size_t)gm * DMODEL + col];
          oh[(size_t)gm * DMODEL + col] = (bf16)y;
        }
      }
    }
  }
}

// ---- masked attention: frozen round-15 structure + micro-cuts ----
// (1) V^T k-interleaved: PV fragment = ONE ds_read_b128 (was 2x b64 + regs
//     assembly) -- DS ops 24->16/tile, zero operand-pack movs.
// (2) #pragma unroll 2: `cur` compile-time per copy -> LDS addresses
//     loop-invariant (gentle unroll; round-12's spill was 16x + preload).
// (3) mask pair as one uint2 load -> vmcnt queue [stage x4][mask x1][pre x4];
//     counted wait vmcnt(5) retires exactly tile-kt's stage loads.
__global__ __launch_bounds__(256, 4) void k_attn(const bf16* __restrict__ Qb,
    const bf16* __restrict__ Kb, const bf16* __restrict__ Vtg,
    const u64* __restrict__ maskb, bf16* __restrict__ attn_out) {
  __shared__ bf16 Kl[2][64 * 64];
  __shared__ bf16 Vt[2][64 * 64];

  int bid = blockIdx.x;
  int work = ((bid & 7) << 7) | (bid >> 3);  // XCD swizzle (1024 = 8*128, bijective)
  int bh = work >> 4, qb = work & 15;
  int bb = bh >> 3, hh = bh & 7;
  int tid = threadIdx.x, lane = tid & 63, w = tid >> 6;
  int lrow = lane & 15, lg = lane >> 4;
  int rl = lane >> 3;
  int csw = ((lane & 7) ^ rl) << 3;
  int q0w = qb * 64 + w * 16;

  const bf16* Qh = Qb + (size_t)bh * N_SEQ * D_HEAD;
  const bf16* Kh = Kb + (size_t)bh * N_SEQ * D_HEAD;
  const bf16* Vh = Vtg + (size_t)bh * D_HEAD * N_SEQ;  // [d][n'] interleaved
  const u32* m32 = (const u32*)(maskb + (size_t)bb * N_SEQ * 16);

  const bf16* Ksrc = Kh + (size_t)(w * 16 + rl) * D_HEAD + csw;
  const bf16* Vsrc = Vh + (size_t)(w * 16 + rl) * N_SEQ + csw;

  bf16x8 qf0 = *reinterpret_cast<const bf16x8*>(&Qh[(q0w + lrow) * 64 + lg * 8]);
  bf16x8 qf1 = *reinterpret_cast<const bf16x8*>(&Qh[(q0w + lrow) * 64 + 32 + lg * 8]);

  f32x4 o[4];   // o[dblk][r] = O[q=lrow][d=dblk*16+lg*4+r]
#pragma unroll
  for (int d = 0; d < 4; d++) o[d] = f32x4{0.f, 0.f, 0.f, 0.f};
  float ls = 0.f;

#define STAGE(buf, kt0)                                                     \
  {                                                                         \
    _Pragma("unroll") for (int i = 0; i < 2; i++) {                         \
      gload16(Ksrc + (size_t)(kt0) * 64 + i * 512, &Kl[buf][(w * 2 + i) * 512]); \
      gload16(Vsrc + (size_t)i * 8192 + (kt0), &Vt[buf][(w * 2 + i) * 512]);     \
    }                                                                       \
  }

  STAGE(0, 0);

#pragma unroll 2
  for (int kt = 0; kt < 16; kt++) {
    int cur = kt & 1;
    int kt0 = kt << 6;
    int midx = ((q0w + lrow) * 16 + kt) * 2;
    uint2 mw2 = *reinterpret_cast<const uint2*>(&m32[midx]);
    u32 mlo = mw2.x, mhi = mw2.y;

    if (kt < 15) STAGE(cur ^ 1, kt0 + 64);

    // counted wait: queue = [stage_kt x4][mask x1][stage_kt+1 x4]
    __builtin_amdgcn_sched_barrier(0);
    if (kt < 15) { asm volatile("s_waitcnt vmcnt(5)" ::: "memory"); }
    else         { asm volatile("s_waitcnt vmcnt(1)" ::: "memory"); }
    __builtin_amdgcn_sched_barrier(0);
    __builtin_amdgcn_s_barrier();
    __builtin_amdgcn_sched_barrier(0);

    f32x4 sc[4];
#pragma unroll
    for (int t = 0; t < 4; t++) {
      bf16x8 kf0 = *reinterpret_cast<const bf16x8*>(&Kl[cur][sidx(t * 16 + lrow, lg * 8)]);
      bf16x8 kf1 = *reinterpret_cast<const bf16x8*>(&Kl[cur][sidx(t * 16 + lrow, 32 + lg * 8)]);
      sc[t] = f32x4{0.f, 0.f, 0.f, 0.f};
      __builtin_amdgcn_s_setprio(1);
      sc[t] = mfma16(kf0, qf0, sc[t]);
      sc[t] = mfma16(kf1, qf1, sc[t]);
      __builtin_amdgcn_s_setprio(0);
    }

    bf16x8 pa[2];
#pragma unroll
    for (int m = 0; m < 2; m++) {
      u32 mw = m == 0 ? mlo : mhi;
#pragma unroll
      for (int j = 0; j < 8; j++) {
        int sh = ((j >> 2) << 4) + lg * 4 + (j & 3);
        int t = 2 * m + (j >> 2), r = j & 3;
        bool bit = (mw >> sh) & 1u;
        float pv = bit ? exp2f(sc[t][r]) : 0.f;
        ls += pv;
        pa[m][j] = (bf16)pv;
      }
    }

    // PV: one b128 per (d,m) thanks to interleaved V^T
#pragma unroll
    for (int d = 0; d < 4; d++) {
#pragma unroll
      for (int m = 0; m < 2; m++) {
        bf16x8 vf = *reinterpret_cast<const bf16x8*>(
            &Vt[cur][sidx(d * 16 + lrow, m * 32 + lg * 8)]);
        __builtin_amdgcn_s_setprio(1);
        o[d] = mfma16(vf, pa[m], o[d]);
        __builtin_amdgcn_s_setprio(0);
      }
    }

    __builtin_amdgcn_sched_barrier(0);
    asm volatile("s_waitcnt lgkmcnt(0)" ::: "memory");
    __builtin_amdgcn_s_barrier();
    __builtin_amdgcn_sched_barrier(0);
  }

  ls += __shfl_xor(ls, 16);
  ls += __shfl_xor(ls, 32);
  float inv = 1.f / ls;  // l > 0 via self-loop

  int gq = q0w + lrow;
#pragma unroll
  for (int d = 0; d < 4; d++) {
    bf16x4 pk;
#pragma unroll
    for (int r = 0; r < 4; r++) pk[r] = (bf16)(o[d][r] * inv);
    *reinterpret_cast<bf16x4*>(
        &attn_out[((size_t)(bb * N_SEQ + gq)) * DMODEL + hh * 64 + d * 16 + lg * 4]) = pk;
  }
#undef STAGE
}

// ---- row LayerNorm: one block per row, bf16 h input ----
__global__ __launch_bounds__(256) void k_ln(const bf16* __restrict__ hb,
    const float* __restrict__ gamma, const float* __restrict__ beta,
    float* __restrict__ out) {
  int row = blockIdx.x, tid = threadIdx.x;
  bf16x2 v2 = *reinterpret_cast<const bf16x2*>(hb + (size_t)row * DMODEL + tid * 2);
  float vx = (float)v2[0], vy = (float)v2[1];
  float s = vx + vy, ss = vx * vx + vy * vy;
#pragma unroll
  for (int off = 1; off < 64; off <<= 1) {
    s += __shfl_xor(s, off);
    ss += __shfl_xor(ss, off);
  }
  __shared__ float as_[4], ass_[4];
  int w = tid >> 6;
  if ((tid & 63) == 0) { as_[w] = s; ass_[w] = ss; }
  __syncthreads();
  s = as_[0] + as_[1] + as_[2] + as_[3];
  ss = ass_[0] + ass_[1] + ass_[2] + ass_[3];
  float mu = s * (1.f / 512.f);
  float var = ss * (1.f / 512.f) - mu * mu;
  float rstd = rsqrtf(var + 1e-5f);
  float2 g = reinterpret_cast<const float2*>(gamma)[tid];
  float2 bt = reinterpret_cast<const float2*>(beta)[tid];
  float2 o;
  o.x = (vx - mu) * rstd * g.x + bt.x;
  o.y = (vy - mu) * rstd * g.y + bt.y;
  reinterpret_cast<float2*>(out + (size_t)row * DMODEL)[tid] = o;
}

extern "C" void kernel_launch(void* const* d_in, const int* in_sizes, int n_in,
                              void* d_out, int out_size, void* d_ws, size_t ws_size,
                              hipStream_t stream) {
  const float* x     = (const float*)d_in[0];
  const float* adj   = (const float*)d_in[1];
  const float* Wq    = (const float*)d_in[2];
  const float* bq    = (const float*)d_in[3];
  const float* Wk    = (const float*)d_in[4];
  const float* bk    = (const float*)d_in[5];
  const float* Wv    = (const float*)d_in[6];
  const float* bv    = (const float*)d_in[7];
  const float* Wo    = (const float*)d_in[8];
  const float* bo    = (const float*)d_in[9];
  const float* gamma = (const float*)d_in[10];
  const float* beta  = (const float*)d_in[11];

  char* ws = (char*)d_ws;
  bf16* xb    = (bf16*)(ws + OFF_XB);
  bf16* wqkv  = (bf16*)(ws + OFF_WQKV);
  bf16* wo    = (bf16*)(ws + OFF_WO);
  float* bqkv = (float*)(ws + OFF_BQKV);
  bf16* Qb    = (bf16*)(ws + OFF_Q);
  bf16* Kb    = (bf16*)(ws + OFF_K);
  bf16* Vb    = (bf16*)(ws + OFF_V);   // holds interleaved V^T
  u64* maskb  = (u64*)(ws + OFF_MASK);
  bf16* attn  = xb;                    // x_bf16 dead after QKV GEMM
  bf16* hb    = (bf16*)(ws + OFF_Q);   // Q/K dead after attention; h in bf16
  float* out  = (float*)d_out;

  // 1. merged prep (x cvt + weight pack + grid-strided mask build)
  k_prep<<<dim3(PREP_X_BLK + PREP_W_BLK + PREP_M_BLK), dim3(256), 0, stream>>>(
      x, adj, Wq, Wk, Wv, Wo, bq, bk, bv, xb, wqkv, wo, bqkv, maskb);

  // 2. QKV projection (M=8192, N=1536), V stored interleaved-transposed
  k_gemm<<<dim3((M_ROWS / 128) * (1536 / 128)), dim3(256), 0, stream>>>(
      xb, wqkv, 1536, 0, bqkv, nullptr, Qb, Kb, Vb, nullptr);

  // 3. masked attention (frozen structure + b128 PV + unroll 2)
  k_attn<<<dim3(1024), dim3(256), 0, stream>>>(Qb, Kb, Vb, maskb, attn);

  // 4. output projection + bias + residual -> h bf16 (M=8192, N=512)
  k_gemm<<<dim3((M_ROWS / 128) * (512 / 128)), dim3(256), 0, stream>>>(
      attn, wo, 512, 1, bo, x, nullptr, nullptr, nullptr, hb);

  // 5. LayerNorm
  k_ln<<<dim3(M_ROWS), dim3(256), 0, stream>>>(hb, gamma, beta, out);
}